// Round 12
// baseline (19.246 us; speedup 1.0000x reference)
//
#include <hip/hip_runtime.h>

// MorphTEmbedding R12: per-call W transpose to morph-major Wt[m][r][d]
// (each morph = 256B contiguous), then main kernel reads W via THREE
// coalesced dword loads per wave (4-line bursts) instead of 17+ scattered
// 32B broadcast rows. A/B factors redistributed via ds_bpermute, C via
// readlane. nt stores + DPP LayerNorm as in R10/R11 (14.2us).

#define RANK      8
#define NUM_MORPH 10000
#define EMB       512
#define LN_EPS    1e-5f
#define WPB       4                 // waves per block (256 threads)
#define RSTRIDE   80000             // floats between ranks in original W
#define W_ELEMS   (RANK * NUM_MORPH * 8)   // 640000

typedef float f32x4 __attribute__((ext_vector_type(4)));

template <int CTRL>
__device__ __forceinline__ float dpp_add(float v) {
    return v + __int_as_float(__builtin_amdgcn_update_dpp(
        __float_as_int(v), __float_as_int(v), CTRL, 0xf, 0xf, false));
}
__device__ __forceinline__ float rdlane(float v, int l) {
    return __int_as_float(__builtin_amdgcn_readlane(__float_as_int(v), l));
}
__device__ __forceinline__ float bperm(int byte_addr, float v) {
    return __int_as_float(__builtin_amdgcn_ds_bpermute(byte_addr, __float_as_int(v)));
}

// ---- kernel 1: W[r][m][d] -> Wt[m][r*8+d]; coalesced reads (64 consecutive
// floats per wave per r), local 32B-chunk writes. 8 morphs/wave.
__global__ __launch_bounds__(256) void transpose_w(
    const float* __restrict__ W, float* __restrict__ Wt) {
    const int lane = threadIdx.x & 63;
    const int wv   = threadIdx.x >> 6;
    const int m    = blockIdx.x * 32 + wv * 8 + (lane >> 3);
    const int d    = lane & 7;
    if (m >= NUM_MORPH) return;
#pragma unroll
    for (int r = 0; r < RANK; ++r)
        Wt[m * 64 + r * 8 + d] = W[r * RSTRIDE + m * 8 + d];
}

// ---- kernel 2: one wave per token ----
// TRANSPOSED: 3 coalesced loads from Wt + bpermute/readlane redistribution.
// Fallback (!TRANSPOSED): R11's broadcast-load path from original W.
template <bool TRANSPOSED>
__global__ __launch_bounds__(256) void morph_emb_kernel(
    const int* __restrict__ x,       // [n_tok]
    const int* __restrict__ co,      // [NUM_SURF, 3]
    const float* __restrict__ Wp,    // Wt (morph-major) or W (rank-major)
    const float* __restrict__ lns,   // [512]
    const float* __restrict__ lnb,   // [512]
    float* __restrict__ out,         // [n_tok, 512]
    int n_tok) {
    const int lane = threadIdx.x & 63;
    const int wid  = blockIdx.x * WPB + (threadIdx.x >> 6);
    const int tok  = (wid < n_tok) ? wid : (n_tok - 1);   // clamp, no divergence

    // token chain (wave-uniform -> s_load)
    const int s  = x[tok];
    const int m0 = co[s * 3 + 0];
    const int m1 = co[s * 3 + 1];
    const int m2 = co[s * 3 + 2];

    // element layout: e = lane*8 + j  =>  a=lane>>3, b=lane&7, c=j
    float p[RANK];        // p[r] = A[r][a] * B[r][b]
    float c_mine;         // lane (r=lane>>3,d=lane&7) holds C-block val [r][d]
    if (TRANSPOSED) {
        // THREE coalesced 256B loads (4-line bursts each)
        const float a_vec = Wp[m0 * 64 + lane];
        const float b_vec = Wp[m1 * 64 + lane];
        c_mine            = Wp[m2 * 64 + lane];
        const int a4 = (lane >> 3) << 2;      // byte addr of lane a
        const int b4 = (lane & 7) << 2;
#pragma unroll
        for (int r = 0; r < RANK; ++r)
            p[r] = bperm(a4 + r * 32, a_vec) * bperm(b4 + r * 32, b_vec);
    } else {
        c_mine = Wp[(size_t)(lane >> 3) * RSTRIDE + (size_t)m2 * 8 + (lane & 7)];
        const float* pa = Wp + (size_t)m0 * 8 + (lane >> 3);
        const float* pb = Wp + (size_t)m1 * 8 + (lane & 7);
#pragma unroll
        for (int r = 0; r < RANK; ++r)
            p[r] = pa[r * RSTRIDE] * pb[r * RSTRIDE];
    }

    // LN params: e = lane*8 -> 4 dwordx4 loads
    const int e = lane << 3;
    const f32x4 g0 = *reinterpret_cast<const f32x4*>(lns + e);
    const f32x4 g1 = *reinterpret_cast<const f32x4*>(lns + e + 4);
    const f32x4 b0 = *reinterpret_cast<const f32x4*>(lnb + e);
    const f32x4 b1 = *reinterpret_cast<const f32x4*>(lnb + e + 4);

    // acc[j] = sum_r p[r] * C[r][j]; C via readlane (const idx) -> SGPR FMA
    float acc[8] = {0.f, 0.f, 0.f, 0.f, 0.f, 0.f, 0.f, 0.f};
#pragma unroll
    for (int r = 0; r < RANK; ++r) {
#pragma unroll
        for (int j = 0; j < 8; ++j)
            acc[j] = fmaf(p[r], rdlane(c_mine, r * 8 + j), acc[j]);
    }

    // ---- LayerNorm stats: DPP row-16 reduce + 4 readlanes ----
    float sm = 0.f, sq = 0.f;
#pragma unroll
    for (int j = 0; j < 8; ++j) { sm += acc[j]; sq += acc[j] * acc[j]; }
    sm = dpp_add<0xB1>(sm);  sq = dpp_add<0xB1>(sq);
    sm = dpp_add<0x4E>(sm);  sq = dpp_add<0x4E>(sq);
    sm = dpp_add<0x141>(sm); sq = dpp_add<0x141>(sq);
    sm = dpp_add<0x140>(sm); sq = dpp_add<0x140>(sq);
    const float tot_s = (rdlane(sm, 0) + rdlane(sm, 16)) +
                        (rdlane(sm, 32) + rdlane(sm, 48));
    const float tot_q = (rdlane(sq, 0) + rdlane(sq, 16)) +
                        (rdlane(sq, 32) + rdlane(sq, 48));
    const float mu = tot_s * (1.0f / EMB);
    const float rs = rsqrtf(tot_q * (1.0f / EMB) - mu * mu + LN_EPS);

    // ---- normalize + store: 2 nontemporal dwordx4 per lane ----
    if (wid < n_tok) {
        f32x4 o0, o1;
        o0[0] = (acc[0] - mu) * rs * g0[0] + b0[0];
        o0[1] = (acc[1] - mu) * rs * g0[1] + b0[1];
        o0[2] = (acc[2] - mu) * rs * g0[2] + b0[2];
        o0[3] = (acc[3] - mu) * rs * g0[3] + b0[3];
        o1[0] = (acc[4] - mu) * rs * g1[0] + b1[0];
        o1[1] = (acc[5] - mu) * rs * g1[1] + b1[1];
        o1[2] = (acc[6] - mu) * rs * g1[2] + b1[2];
        o1[3] = (acc[7] - mu) * rs * g1[3] + b1[3];
        f32x4* op = reinterpret_cast<f32x4*>(out + (size_t)wid * EMB + e);
        __builtin_nontemporal_store(o0, op);
        __builtin_nontemporal_store(o1, op + 1);
    }
}

extern "C" void kernel_launch(void* const* d_in, const int* in_sizes, int n_in,
                              void* d_out, int out_size, void* d_ws, size_t ws_size,
                              hipStream_t stream) {
    const int*   x   = (const int*)d_in[0];
    const int*   co  = (const int*)d_in[1];
    const float* W   = (const float*)d_in[2];
    const float* lns = (const float*)d_in[3];
    const float* lnb = (const float*)d_in[4];
    float*       out = (float*)d_out;

    const int n_tok  = in_sizes[0];                 // 16384
    const int blocks = (n_tok + WPB - 1) / WPB;     // 4096

    if (ws_size >= (size_t)W_ELEMS * sizeof(float)) {
        float* Wt = (float*)d_ws;
        transpose_w<<<(NUM_MORPH + 31) / 32, 256, 0, stream>>>(W, Wt);
        morph_emb_kernel<true><<<blocks, WPB * 64, 0, stream>>>(
            x, co, Wt, lns, lnb, out, n_tok);
    } else {
        morph_emb_kernel<false><<<blocks, WPB * 64, 0, stream>>>(
            x, co, W, lns, lnb, out, n_tok);
    }
}

// Round 13
// 14.412 us; speedup vs baseline: 1.3354x; 1.3354x over previous
//
#include <hip/hip_runtime.h>

// MorphTEmbedding R13: 4 tokens per wave -> 4096 waves = 4/SIMD = ONE
// occupancy generation (R11's 16384 waves = 2 generations, chain latency
// paid twice). All 12 gather loads (4 tokens x {A,B,C} 8x8 blocks) issued
// upfront as independent chains; A/B redistributed in-wave via ds_bpermute,
// C via compile-time readlane. nt stores + DPP LayerNorm as in R11.

#define RANK      8
#define NUM_MORPH 10000
#define EMB       512
#define LN_EPS    1e-5f
#define WPB       4                 // waves per block (256 threads)
#define TPW       4                 // tokens per wave
#define RSTRIDE   80000             // floats between ranks in W

typedef float f32x4 __attribute__((ext_vector_type(4)));

template <int CTRL>
__device__ __forceinline__ float dpp_add(float v) {
    return v + __int_as_float(__builtin_amdgcn_update_dpp(
        __float_as_int(v), __float_as_int(v), CTRL, 0xf, 0xf, false));
}
__device__ __forceinline__ float rdlane(float v, int l) {
    return __int_as_float(__builtin_amdgcn_readlane(__float_as_int(v), l));
}
__device__ __forceinline__ float bperm(int byte_addr, float v) {
    return __int_as_float(__builtin_amdgcn_ds_bpermute(byte_addr, __float_as_int(v)));
}

__global__ __launch_bounds__(256) void morph_emb_kernel(
    const int* __restrict__ x,       // [n_tok]
    const int* __restrict__ co,      // [NUM_SURF, 3]
    const float* __restrict__ W,     // [RANK, NUM_MORPH, 8]
    const float* __restrict__ lns,   // [512]
    const float* __restrict__ lnb,   // [512]
    float* __restrict__ out,         // [n_tok, 512]
    int n_tok) {
    const int lane = threadIdx.x & 63;
    const int wid  = blockIdx.x * WPB + (threadIdx.x >> 6);
    const int t0   = wid * TPW;

    // lane's block coordinates (layout e = lane*8 + j: a=lane>>3, b=lane&7)
    const int r_ln = lane >> 3;       // this lane's row in the 8x8 block
    const int d_ln = lane & 7;        // this lane's col in the 8x8 block
    const size_t gofs = (size_t)r_ln * RSTRIDE + d_ln;  // gather offset

    // ---- 4 independent token chains, all gathers issued upfront ----
    int s_[TPW], m0_[TPW], m1_[TPW], m2_[TPW];
#pragma unroll
    for (int t = 0; t < TPW; ++t) {
        int tt = t0 + t; if (tt >= n_tok) tt = n_tok - 1;
        s_[t]  = x[tt];
    }
#pragma unroll
    for (int t = 0; t < TPW; ++t) {
        m0_[t] = co[s_[t] * 3 + 0];
        m1_[t] = co[s_[t] * 3 + 1];
        m2_[t] = co[s_[t] * 3 + 2];
    }
    // 12 independent gather loads: lane (r_ln, d_ln) of each 8x8 block
    float am[TPW], bm[TPW], cm[TPW];
#pragma unroll
    for (int t = 0; t < TPW; ++t) {
        am[t] = W[gofs + (size_t)m0_[t] * 8];
        bm[t] = W[gofs + (size_t)m1_[t] * 8];
        cm[t] = W[gofs + (size_t)m2_[t] * 8];
    }

    // LN params (token-invariant): 4 dwordx4 loads
    const int e = lane << 3;
    const f32x4 g0 = *reinterpret_cast<const f32x4*>(lns + e);
    const f32x4 g1 = *reinterpret_cast<const f32x4*>(lns + e + 4);
    const f32x4 b0 = *reinterpret_cast<const f32x4*>(lnb + e);
    const f32x4 b1 = *reinterpret_cast<const f32x4*>(lnb + e + 4);

    // ---- in-wave redistribution + compute ----
    // p[t][r] = A[r][a]*B[r][b]: A[r][a] lives in lane r*8+a of am[t]
    const int aaddr = r_ln << 2;      // byte addr of lane (a = lane>>3)
    const int baddr = d_ln << 2;      // byte addr of lane (b = lane&7)
    float acc[TPW][8] = {};
#pragma unroll
    for (int r = 0; r < RANK; ++r) {
#pragma unroll
        for (int t = 0; t < TPW; ++t) {
            const float p = bperm(aaddr + r * 32, am[t]) *
                            bperm(baddr + r * 32, bm[t]);
#pragma unroll
            for (int j = 0; j < 8; ++j)
                acc[t][j] = fmaf(p, rdlane(cm[t], r * 8 + j), acc[t][j]);
        }
    }

    // ---- LayerNorm stats: 8 interleaved DPP chains ----
    float sm[TPW], sq[TPW];
#pragma unroll
    for (int t = 0; t < TPW; ++t) {
        float s = 0.f, q = 0.f;
#pragma unroll
        for (int j = 0; j < 8; ++j) { s += acc[t][j]; q += acc[t][j] * acc[t][j]; }
        sm[t] = s; sq[t] = q;
    }
#pragma unroll
    for (int t = 0; t < TPW; ++t) {
        sm[t] = dpp_add<0xB1>(sm[t]);  sq[t] = dpp_add<0xB1>(sq[t]);
        sm[t] = dpp_add<0x4E>(sm[t]);  sq[t] = dpp_add<0x4E>(sq[t]);
        sm[t] = dpp_add<0x141>(sm[t]); sq[t] = dpp_add<0x141>(sq[t]);
        sm[t] = dpp_add<0x140>(sm[t]); sq[t] = dpp_add<0x140>(sq[t]);
    }

    // ---- normalize + store: 2 nt dwordx4 per token ----
#pragma unroll
    for (int t = 0; t < TPW; ++t) {
        const float ts = (rdlane(sm[t], 0) + rdlane(sm[t], 16)) +
                         (rdlane(sm[t], 32) + rdlane(sm[t], 48));
        const float tq = (rdlane(sq[t], 0) + rdlane(sq[t], 16)) +
                         (rdlane(sq[t], 32) + rdlane(sq[t], 48));
        const float mu = ts * (1.0f / EMB);
        const float rs = rsqrtf(tq * (1.0f / EMB) - mu * mu + LN_EPS);
        if (t0 + t < n_tok) {
            f32x4 o0, o1;
            o0[0] = (acc[t][0] - mu) * rs * g0[0] + b0[0];
            o0[1] = (acc[t][1] - mu) * rs * g0[1] + b0[1];
            o0[2] = (acc[t][2] - mu) * rs * g0[2] + b0[2];
            o0[3] = (acc[t][3] - mu) * rs * g0[3] + b0[3];
            o1[0] = (acc[t][4] - mu) * rs * g1[0] + b1[0];
            o1[1] = (acc[t][5] - mu) * rs * g1[1] + b1[1];
            o1[2] = (acc[t][6] - mu) * rs * g1[2] + b1[2];
            o1[3] = (acc[t][7] - mu) * rs * g1[3] + b1[3];
            f32x4* op = reinterpret_cast<f32x4*>(out + (size_t)(t0 + t) * EMB + e);
            __builtin_nontemporal_store(o0, op);
            __builtin_nontemporal_store(o1, op + 1);
        }
    }
}

extern "C" void kernel_launch(void* const* d_in, const int* in_sizes, int n_in,
                              void* d_out, int out_size, void* d_ws, size_t ws_size,
                              hipStream_t stream) {
    const int*   x   = (const int*)d_in[0];
    const int*   co  = (const int*)d_in[1];
    const float* W   = (const float*)d_in[2];
    const float* lns = (const float*)d_in[3];
    const float* lnb = (const float*)d_in[4];
    float*       out = (float*)d_out;

    const int n_tok = in_sizes[0];                           // 16384
    const int tok_per_block = WPB * TPW;                     // 16
    const int blocks = (n_tok + tok_per_block - 1) / tok_per_block;  // 1024
    morph_emb_kernel<<<blocks, WPB * 64, 0, stream>>>(x, co, W, lns, lnb, out, n_tok);
}